// Round 12
// baseline (269.535 us; speedup 1.0000x reference)
//
#include <hip/hip_runtime.h>

typedef float v2f __attribute__((ext_vector_type(2)));

#define NEG_INF (-__builtin_huge_valf())

// -inf virtual row: OOB x rows redirect here with chunk-stride 0.
#define N8 NEG_INF,NEG_INF,NEG_INF,NEG_INF,NEG_INF,NEG_INF,NEG_INF,NEG_INF
__constant__ __align__(16) float NINF_ROW[64] = {N8,N8,N8,N8,N8,N8,N8,N8};
#undef N8

#define CCH   4                 // c's per LDS chunk
#define ROWS  6                 // 4 output rows + h halo
#define XSTR  64                // xs row stride: pure float4, b128-balanced
#define SLOTS 6                 // CCH*ROWS*16 float4 / 64 threads

// Pure compiler fence: orders LDS/global ops at IR level, emits NO
// instructions. Hardware DS ops retire in-order within a wave, so for a
// single-wave block program order == hardware order; only the compiler
// could break it (round-6 lesson). Unlike __syncthreads this does NOT
// force vmcnt(0)/lgkmcnt(0) drains -> partial waitcnts, deeper pipeline.
#define CFENCE() asm volatile("" ::: "memory")

__device__ __forceinline__ float dpp_shr1(float v, float old) {   // wg <- wg-1
    return __int_as_float(__builtin_amdgcn_update_dpp(
        __float_as_int(old), __float_as_int(v), 0x111, 0xF, 0xF, false));
}
__device__ __forceinline__ float dpp_shl1(float v, float old) {   // wg <- wg+1
    return __int_as_float(__builtin_amdgcn_update_dpp(
        __float_as_int(old), __float_as_int(v), 0x101, 0xF, 0xF, false));
}

// Wave-per-tile (64 threads), 2o x 1h x 4w = 8 acc/thread, R8 compute core.
// NEW: 2-chunk-deep global prefetch (R0/R1, unroll-by-2 -> no rotate movs)
// + fence-only ordering (no syncthreads) -> ~1700 cy latency cover and no
// per-chunk full vmcnt/lgkmcnt drains.
__global__ __launch_bounds__(64, 4)
void maxplus_conv2d_kernel(const float* __restrict__ x,
                           const float* __restrict__ kern,
                           float* __restrict__ out) {
    __shared__ float xs[CCH * ROWS * XSTR];   // 6144 B

    const int tid = threadIdx.x;        // 0..63
    const int wg  = tid & 15;
    const int hr  = tid >> 4;           // 0..3
    const int w0  = wg << 2;

    const int h_base = blockIdx.x * 4;
    const int b      = blockIdx.y;
    const int o_base = blockIdx.z << 1; // o pair

    // ---- staging slots (chunk-invariant; computed once) ----
    const float* xb = x + (size_t)b * 64 * 64 * 64;
    const float* gsrc[SLOTS];           // points at last-loaded chunk's addr
    float*       xdst[SLOTS];
    int          gstr[SLOTS];           // advance per chunk (floats); 0 if OOB row
#pragma unroll
    for (int k = 0; k < SLOTS; ++k) {
        int rowid = k * 4 + hr;           // 0..23, each exactly once per wave
        int cl    = rowid / ROWS;
        int r     = rowid - cl * ROWS;
        int gh    = h_base + r - 1;       // -1..64
        bool valid = (unsigned)gh < 64u;
        gsrc[k]  = valid ? (xb + ((size_t)cl * 64 + gh) * 64 + wg * 4)
                         : (NINF_ROW + wg * 4);
        gstr[k]  = valid ? CCH * 64 * 64 : 0;
        xdst[k]  = &xs[rowid * XSTR + wg * 4];   // aligned ds_write_b128
    }

    const float ninf = NEG_INF;

    float acc[2][4];
#pragma unroll
    for (int oo = 0; oo < 2; ++oo)
#pragma unroll
        for (int wi = 0; wi < 4; ++wi)
            acc[oo][wi] = NEG_INF;

    // prefetch chunks 0 and 1 (two groups in flight from the start)
    float4 R0[SLOTS], R1[SLOTS];
#pragma unroll
    for (int k = 0; k < SLOTS; ++k) R0[k] = *(const float4*)gsrc[k];
#pragma unroll
    for (int k = 0; k < SLOTS; ++k) {
        gsrc[k] += gstr[k];
        R1[k] = *(const float4*)gsrc[k];
    }

    // one compute chunk: taps (uniform s_load) + R8's proven max3 core
    auto compute_chunk = [&](int c0) {
        float kv[CCH][2][9];
#pragma unroll
        for (int cl = 0; cl < CCH; ++cl)
#pragma unroll
            for (int oo = 0; oo < 2; ++oo) {
                const float* kp = kern + ((size_t)(o_base + oo) * 64 + (c0 + cl)) * 9;
#pragma unroll
                for (int t = 0; t < 9; ++t) kv[cl][oo][t] = kp[t];
            }

#pragma unroll
        for (int cl = 0; cl < CCH; ++cl) {
#pragma unroll
            for (int r = 0; r < 3; ++r) {
                const int rowid = cl * ROWS + hr + r;
                float4 m = *(const float4*)(&xs[rowid * XSTR + w0]);
                float le = dpp_shr1(m.w, ninf);   // col w0-1 (wg==0 -> -inf)
                float re = dpp_shl1(m.x, ninf);   // col w0+4 (wg==15 -> -inf)

                v2f P0 = {le,  m.x};   // window idx (0,1)
                v2f P1 = {m.y, m.z};   // (2,3)
                v2f P2 = {m.w, re };   // (4,5)
                v2f Q0 = {m.x, m.y};   // (1,2)
                v2f Q1 = {m.z, m.w};   // (3,4)

#pragma unroll
                for (int oo = 0; oo < 2; ++oo) {
                    const float* k9 = kv[cl][oo];
                    v2f ka = {k9[3*r+0], k9[3*r+0]};
                    v2f kb = {k9[3*r+1], k9[3*r+1]};
                    v2f kc = {k9[3*r+2], k9[3*r+2]};
                    v2f a0 = P0 + ka, b0 = P1 + ka;   // kj=0
                    v2f a1 = Q0 + kb, b1 = Q1 + kb;   // kj=1
                    v2f a2 = P1 + kc, b2 = P2 + kc;   // kj=2

                    acc[oo][0] = fmaxf(acc[oo][0], fmaxf(fmaxf(a0.x, a1.x), a2.x));
                    acc[oo][1] = fmaxf(acc[oo][1], fmaxf(fmaxf(a0.y, a1.y), a2.y));
                    acc[oo][2] = fmaxf(acc[oo][2], fmaxf(fmaxf(b0.x, b1.x), b2.x));
                    acc[oo][3] = fmaxf(acc[oo][3], fmaxf(fmaxf(b0.y, b1.y), b2.y));
                }
            }
        }
    };

#pragma unroll 1
    for (int cc = 0; cc < 64; cc += 2 * CCH) {
        // ---- body A: stage chunk cc (from R0), refill R0 <- chunk cc+8 ----
        CFENCE();   // prev compute's ds_reads stay before these writes
#pragma unroll
        for (int k = 0; k < SLOTS; ++k) *(float4*)xdst[k] = R0[k];
        CFENCE();   // writes stay before this chunk's ds_reads
        if (cc + 8 < 64) {
#pragma unroll
            for (int k = 0; k < SLOTS; ++k) {
                gsrc[k] += gstr[k];
                R0[k] = *(const float4*)gsrc[k];
            }
        }
        compute_chunk(cc);

        // ---- body B: stage chunk cc+4 (from R1), refill R1 <- chunk cc+12 ----
        CFENCE();
#pragma unroll
        for (int k = 0; k < SLOTS; ++k) *(float4*)xdst[k] = R1[k];
        CFENCE();
        if (cc + 12 < 64) {
#pragma unroll
            for (int k = 0; k < SLOTS; ++k) {
                gsrc[k] += gstr[k];
                R1[k] = *(const float4*)gsrc[k];
            }
        }
        compute_chunk(cc + 4);
    }

    const int h = h_base + hr;
#pragma unroll
    for (int oo = 0; oo < 2; ++oo) {
        float4 v = make_float4(acc[oo][0], acc[oo][1], acc[oo][2], acc[oo][3]);
        *(float4*)(out + ((((size_t)b * 64 + (o_base + oo)) * 64 + h) * 64 + w0)) = v;
    }
}

extern "C" void kernel_launch(void* const* d_in, const int* in_sizes, int n_in,
                              void* d_out, int out_size, void* d_ws, size_t ws_size,
                              hipStream_t stream) {
    const float* x    = (const float*)d_in[0];   // [8,64,64,64]
    const float* kern = (const float*)d_in[1];   // [64,64,3,3]
    float* out = (float*)d_out;                  // [8,64,64,64]

    dim3 grid(16, 8, 32);   // h-tiles, b, o-pairs
    dim3 block(64);
    maxplus_conv2d_kernel<<<grid, block, 0, stream>>>(x, kern, out);
}